// Round 4
// baseline (287.102 us; speedup 1.0000x reference)
//
#include <hip/hip_runtime.h>
#include <cmath>

constexpr int S_LEN = 2048;
constexpr float EPS = 1e-8f;

typedef unsigned uvec32 __attribute__((ext_vector_type(32)));

__device__ __forceinline__ float fin(float v) { return isfinite(v) ? v : 0.0f; }
__device__ __forceinline__ float rcpf(float x) { return __builtin_amdgcn_rcpf(x); }

__device__ __forceinline__ unsigned f2o_bits(unsigned u) {
    return (u & 0x80000000u) ? ~u : (u | 0x80000000u);
}
__device__ __forceinline__ float o2f(unsigned u) {
    return __uint_as_float((u & 0x80000000u) ? (u ^ 0x80000000u) : ~u);
}

// ---- DPP helpers (ctrl/rmask are ICEs via template params) ----
template <int Ctrl, int Rmask>
__device__ __forceinline__ int dpp_zero_i(int x) {
    return __builtin_amdgcn_update_dpp(0, x, Ctrl, Rmask, 0xF, true);
}
template <int Ctrl>
__device__ __forceinline__ int dpp_keep_i(int x) {
    return __builtin_amdgcn_update_dpp(x, x, Ctrl, 0xF, 0xF, false);
}
// shfl_down(x,1) across the wave: wave_shl1 (0x130) = dest i <- src i+1,
// bound_ctrl zero-fill -> lane 63 gets 0. (Direction derived from the verified
// wred chain: row_shr:N = dest i <- src i-N, so wave_shl is the opposite.)
__device__ __forceinline__ float dpp_shdn1_f(float x) {
    return __uint_as_float((unsigned)dpp_zero_i<0x130, 0xF>((int)__float_as_uint(x)));
}
__device__ __forceinline__ int wred_add_i(int v) {
    v += dpp_zero_i<0xB1, 0xF>(v);
    v += dpp_zero_i<0x4E, 0xF>(v);
    v += dpp_zero_i<0x114, 0xF>(v);
    v += dpp_zero_i<0x118, 0xF>(v);
    v += dpp_zero_i<0x142, 0xA>(v);
    v += dpp_zero_i<0x143, 0xC>(v);
    return __builtin_amdgcn_readlane(v, 63);
}
__device__ __forceinline__ float wred_add_f(float v) {
    #define ADDF(CT, RM) v += __uint_as_float((unsigned)dpp_zero_i<CT, RM>((int)__float_as_uint(v)))
    ADDF(0xB1, 0xF); ADDF(0x4E, 0xF); ADDF(0x114, 0xF);
    ADDF(0x118, 0xF); ADDF(0x142, 0xA); ADDF(0x143, 0xC);
    #undef ADDF
    return __uint_as_float((unsigned)__builtin_amdgcn_readlane((int)__float_as_uint(v), 63));
}
__device__ __forceinline__ float wred_min_f(float v) {
    #define MINF(CT) v = fminf(v, __uint_as_float((unsigned)dpp_keep_i<CT>((int)__float_as_uint(v))))
    MINF(0xB1); MINF(0x4E); MINF(0x114); MINF(0x118); MINF(0x142); MINF(0x143);
    #undef MINF
    return __uint_as_float((unsigned)__builtin_amdgcn_readlane((int)__float_as_uint(v), 63));
}
__device__ __forceinline__ float wred_max_f(float v) {
    #define MAXF(CT) v = fmaxf(v, __uint_as_float((unsigned)dpp_keep_i<CT>((int)__float_as_uint(v))))
    MAXF(0xB1); MAXF(0x4E); MAXF(0x114); MAXF(0x118); MAXF(0x142); MAXF(0x143);
    #undef MAXF
    return __uint_as_float((unsigned)__builtin_amdgcn_readlane((int)__float_as_uint(v), 63));
}
__device__ __forceinline__ unsigned wred_umin(unsigned v) {
    #define MINU(CT) { unsigned t = (unsigned)dpp_keep_i<CT>((int)v); v = v < t ? v : t; }
    MINU(0xB1) MINU(0x4E) MINU(0x114) MINU(0x118) MINU(0x142) MINU(0x143)
    #undef MINU
    return (unsigned)__builtin_amdgcn_readlane((int)v, 63);
}
__device__ __forceinline__ float readlane_f(float x, int l) {
    return __uint_as_float((unsigned)__builtin_amdgcn_readlane((int)__float_as_uint(x), l));
}

// Hacker's Delight 32x32 bit transpose (anti-diagonal; involution).
// j=16, j=8 via v_perm_b32 (byte shuffles); j=4,2,1 via bfi masked-merge:
// A' = ((B>>j)&m)|(A&~m);  B' = ((A<<j)&~m)|(B&m)   [note m<<j == ~m here]
__device__ __forceinline__ void transpose32(uvec32& A) {
    #pragma unroll
    for (int k = 0; k < 16; k++) {
        unsigned lo = __builtin_amdgcn_perm(A[k], A[k + 16], 0x07060302u);
        unsigned hi = __builtin_amdgcn_perm(A[k], A[k + 16], 0x05040100u);
        A[k] = lo; A[k + 16] = hi;
    }
    #pragma unroll
    for (int k0 = 0; k0 < 32; k0 += 16) {
        #pragma unroll
        for (int k = k0; k < k0 + 8; k++) {
            unsigned lo = __builtin_amdgcn_perm(A[k], A[k + 8], 0x07030501u);
            unsigned hi = __builtin_amdgcn_perm(A[k], A[k + 8], 0x06020400u);
            A[k] = lo; A[k + 8] = hi;
        }
    }
    #pragma unroll
    for (int j = 4; j; j >>= 1) {
        const unsigned m = (j == 4) ? 0x0F0F0F0Fu : (j == 2) ? 0x33333333u : 0x55555555u;
        #pragma unroll
        for (int k = 0; k < 32; k++) {
            if (!(k & j)) {
                unsigned Ak = A[k], Bk = A[k | j];
                A[k]     = ((Bk >> j) & m) | (Ak & ~m);
                A[k | j] = ((Ak << j) & ~m) | (Bk & m);
            }
        }
    }
}

#define VF(e) __uint_as_float(a[e])

// ============ K0: transpose W1 once into d_ws ============
// wt[0:1280) = W1T (20 x 64): W1T[k*64+j] = W1[j*20+k]
__global__ __launch_bounds__(256) void transpose_w_kernel(
    const float* __restrict__ W1, float* __restrict__ wt)
{
    int tid = blockIdx.x * blockDim.x + threadIdx.x;
    int stride = gridDim.x * blockDim.x;
    for (int n = tid; n < 64 * 20; n += stride) {
        int j = n & 63, k = n >> 6;
        wt[n] = W1[j * 20 + k];
    }
}

// ============ K1: stats + percentiles + fused per-row MLP (wave/row) ============
// feats order (LDS sf slots): 0 mean, 1 std, 2 min, 3 max, 4 median, 5 trend,
// 6 ac1, 7 ac7, 8 ac24, 9 cv, 10 iqr, 11 seasonal, 12 skew, 13 kurt, 14 len,
// 15 sad, 16 madiff, 17 std_diff, 18 p25, 19 p75
__global__ __launch_bounds__(256, 6) void fused_stats_mlp_kernel(
    const float* __restrict__ x, const float* __restrict__ wt,
    const float* __restrict__ b1, const float* __restrict__ W2,
    const float* __restrict__ b2, float* __restrict__ out, int nrows)
{
    __shared__ __align__(16) float sf[4][20];   // per-wave feature stash (wave-uniform)
    __shared__ __align__(16) float hsh[4][64];  // per-wave hidden layer

    const int gw   = (blockIdx.x * 256 + threadIdx.x) >> 6;  // row
    const int lane = threadIdx.x & 63;
    const int w    = (threadIdx.x >> 6);
    if (gw >= nrows) return;

    uvec32 a;
    const float* xr = x + (size_t)gw * S_LEN + lane * 32;
    #pragma unroll
    for (int q = 0; q < 8; q++) {
        float4 t = reinterpret_cast<const float4*>(xr)[q];
        a[4 * q + 0] = __float_as_uint(t.x); a[4 * q + 1] = __float_as_uint(t.y);
        a[4 * q + 2] = __float_as_uint(t.z); a[4 * q + 3] = __float_as_uint(t.w);
    }

    // ---------------- phase 1: streaming stats (raw moments) ----------------
    float s1 = 0.f, s2 = 0.f, s3 = 0.f, s4 = 0.f, sd2 = 0.f, sad = 0.f;
    float p1 = 0.f, p7 = 0.f, p24 = 0.f, se1 = 0.f, se2 = 0.f;
    float mn = VF(0), mx = VF(0);
    #pragma unroll
    for (int e = 0; e < 32; e++) {
        float val = VF(e);
        float t = val * val;
        s1 += val; s2 += t;
        s3 = fmaf(t, val, s3); s4 = fmaf(t, t, s4);
        mn = fminf(mn, val); mx = fmaxf(mx, val);
    }
    #pragma unroll
    for (int e = 0; e < 31; e++) {
        float d = VF(e + 1) - VF(e);
        sd2 = fmaf(d, d, sd2); sad += fabsf(d);
        p1 = fmaf(VF(e), VF(e + 1), p1);
    }
    #pragma unroll
    for (int e = 0; e < 25; e++) p7 = fmaf(VF(e), VF(e + 7), p7);
    #pragma unroll
    for (int e = 0; e < 8; e++)  p24 = fmaf(VF(e), VF(e + 24), p24);

    const bool notlast = (lane < 63);
    #pragma unroll
    for (int j = 0; j < 24; j++) {
        float g = dpp_shdn1_f(VF(j));          // lane 63 -> 0
        p24 = fmaf(VF(8 + j), g, p24);
        if (j < 7) p7 = fmaf(VF(25 + j), g, p7);
        if (j == 0) {
            float d = g - VF(31);
            float dm = notlast ? d : 0.f;
            sd2 = fmaf(dm, dm, sd2); sad += fabsf(dm);
            p1 = fmaf(VF(31), g, p1);
        }
    }
    {   // seasonal x[::24]
        int r3 = lane % 3;
        float sv = (r3 == 0) ? VF(0) : ((r3 == 1) ? VF(16) : VF(8));
        se1 += sv; se2 = fmaf(sv, sv, se2);
        if (r3 == 0) { se1 += VF(24); se2 = fmaf(VF(24), VF(24), se2); }
    }
    // head (lane 0 forward) and tail (lane 63 reversed) partials in one loop
    const bool is63 = (lane == 63);
    float acc1 = 0.f, acc2 = 0.f, ck1 = 0.f, ck2 = 0.f;
    #pragma unroll
    for (int i = 0; i < 24; i++) {
        float pick = is63 ? VF(31 - i) : VF(i);
        acc1 += pick; acc2 = fmaf(pick, pick, acc2);
        if (i == 6) { ck1 = acc1; ck2 = acc2; }
    }
    const float h1  = readlane_f(VF(0), 0),   t1  = readlane_f(VF(31), 63);
    const float h7  = readlane_f(ck1, 0),     hq7 = readlane_f(ck2, 0);
    const float h24 = readlane_f(acc1, 0),    hq24 = readlane_f(acc2, 0);
    const float t7  = readlane_f(ck1, 63),    tq7 = readlane_f(ck2, 63);
    const float t24 = readlane_f(acc1, 63),   tq24 = readlane_f(acc2, 63);
    const float hq1 = h1 * h1, tq1 = t1 * t1;

    float S1  = wred_add_f(s1);
    float S2  = wred_add_f(s2);
    float S3  = wred_add_f(s3);
    float S4  = wred_add_f(s4);
    float SD2 = wred_add_f(sd2);
    float SAD = wred_add_f(sad);
    float P1  = wred_add_f(p1);
    float P7  = wred_add_f(p7);
    float P24 = wred_add_f(p24);
    float SE1 = wred_add_f(se1);
    float SE2 = wred_add_f(se2);
    float MN  = wred_min_f(mn);
    float MX  = wred_max_f(mx);

    // 16 stat features -> LDS stash NOW (frees registers across the select)
    {
        constexpr float invS  = 1.0f / 2048.0f;   // exact (pow2)
        constexpr float invND = 1.0f / 2047.0f;
        const float Sf = (float)S_LEN;
        float mu = S1 * invS;
        float q2 = S2 * invS, q3 = S3 * invS, q4 = S4 * invS;
        float mu2 = mu * mu;
        float m2v = q2 - mu2;
        float m3v = q3 - 3.f * mu * q2 + 2.f * mu * mu2;
        float m4v = q4 - 4.f * mu * q3 + 6.f * mu2 * q2 - 3.f * mu2 * mu2;
        float stdv = sqrtf(m2v);
        float dmean = (t1 - h1) * invND;
        float dvar = SD2 * invND - dmean * dmean;
        float std_diff = sqrtf(fmaxf(dvar, 0.f));
        float trend = std_diff * rcpf(stdv + EPS);
        float ac[3];
        const float invN[3] = {1.0f / 2047.0f, 1.0f / 2041.0f, 1.0f / 2024.0f};
        const float Ps[3] = {P1, P7, P24};
        const float hd[3] = {h1, h7, h24},   hqv[3] = {hq1, hq7, hq24};
        const float tl[3] = {t1, t7, t24},   tqv[3] = {tq1, tq7, tq24};
        #pragma unroll
        for (int q = 0; q < 3; q++) {
            float in = invN[q];
            float sa = S1 - tl[q], sb = S1 - hd[q];
            float qa = S2 - tqv[q], qb = S2 - hqv[q];
            float am = sa * in, bm = sb * in;
            float cov = Ps[q] * in - am * bm;
            float as_ = sqrtf(fmaxf(qa * in - am * am, 0.f));
            float bs_ = sqrtf(fmaxf(qb * in - bm * bm, 0.f));
            ac[q] = cov * rcpf(as_ * bs_);
        }
        float cv = stdv * rcpf(fabsf(mu) + EPS);
        float sm = SE1 * (1.0f / 86.0f);
        float svar = SE2 * (1.0f / 86.0f) - sm * sm;
        float seasonal = svar * rcpf(m2v + EPS);
        float skew = m3v * rcpf(m2v * stdv);
        float kurt = m4v * rcpf(m2v * m2v) - 3.f;
        if (lane == 0) {
            float* s = sf[w];
            s[0]  = fin(mu);       s[1]  = fin(stdv);
            s[2]  = fin(MN);       s[3]  = fin(MX);
            s[5]  = fin(trend);    s[6]  = fin(ac[0]);
            s[7]  = fin(ac[1]);    s[8]  = fin(ac[2]);
            s[9]  = fin(cv);       s[11] = fin(seasonal);
            s[12] = fin(skew);     s[13] = fin(kurt);
            s[14] = Sf;            s[15] = fin(SAD);
            s[16] = fin(SAD * invND); s[17] = fin(std_diff);
        }
    }

    // ---------------- phase 2: bit-plane radix select ----------------
    #pragma unroll
    for (int e = 0; e < 32; e++) a[e] = f2o_bits(a[e]);
    transpose32(a);

    // Count ONES (w = act & plane); zeros = cnt - ones; cnt tracked in scalars.
    unsigned act0 = ~0u, act1 = ~0u, act2 = ~0u;
    int K0 = 511, K1 = 1023, K2 = 1535;
    int cnt0 = 2048, cnt1 = 2048, cnt2 = 2048;
    unsigned uK0 = 0, uK1 = 0, uK2 = 0;
    #pragma unroll
    for (int b = 31; b >= 0; b--) {
        unsigned mb = a[31 - b];
        unsigned w0 = act0 & mb, w1 = act1 & mb, w2 = act2 & mb;
        int O01 = wred_add_i(__popc(w0) | (__popc(w1) << 16));
        int O2  = wred_add_i(__popc(w2));
        int c0 = cnt0 - (O01 & 0xFFFF);
        int c1 = cnt1 - (int)((unsigned)O01 >> 16);
        int c2i = cnt2 - O2;
        // branch-free selects (uniform conditions)
        bool t0 = (K0 >= c0), t1c = (K1 >= c1), t2c = (K2 >= c2i);
        act0 = t0  ? w0 : (act0 ^ w0);
        act1 = t1c ? w1 : (act1 ^ w1);
        act2 = t2c ? w2 : (act2 ^ w2);
        cnt0 = t0  ? (cnt0 - c0)  : c0;
        cnt1 = t1c ? (cnt1 - c1)  : c1;
        cnt2 = t2c ? (cnt2 - c2i) : c2i;
        K0 = t0  ? (K0 - c0)  : K0;
        K1 = t1c ? (K1 - c1)  : K1;
        K2 = t2c ? (K2 - c2i) : K2;
        uK0 |= t0  ? (1u << b) : 0u;
        uK1 |= t1c ? (1u << b) : 0u;
        uK2 |= t2c ? (1u << b) : 0u;
    }
    // After bit 0, act marks exactly the elements equal to uK: eq == cnt.
    const int eq0 = cnt0, eq1 = cnt1, eq2 = cnt2;

    transpose32(a);  // involution -> recover orderable values
    // min over {ue > uK} via wrap-around: ue - (uK+1) is small iff ue > uK.
    const unsigned k0p1 = uK0 + 1, k1p1 = uK1 + 1, k2p1 = uK2 + 1;
    unsigned m0 = ~0u, m1 = ~0u, m2 = ~0u;
    #pragma unroll
    for (int e = 0; e < 32; e++) {
        unsigned ue = a[e];
        unsigned d0 = ue - k0p1; m0 = m0 < d0 ? m0 : d0;
        unsigned d1 = ue - k1p1; m1 = m1 < d1 ? m1 : d1;
        unsigned d2 = ue - k2p1; m2 = m2 < d2 ? m2 : d2;
    }
    m0 = wred_umin(m0) + k0p1;
    m1 = wred_umin(m1) + k1p1;
    m2 = wred_umin(m2) + k2p1;

    float v511 = o2f(uK0), v1023 = o2f(uK1), v1535 = o2f(uK2);
    float v512  = (K0 + 1 < eq0) ? v511  : o2f(m0);
    float v1024 = (K1 + 1 < eq1) ? v1023 : o2f(m1);
    float v1536 = (K2 + 1 < eq2) ? v1535 : o2f(m2);
    float p25 = v511 + 0.75f * (v512 - v511);
    float med = 0.5f * (v1023 + v1024);
    float p75 = v1535 + 0.25f * (v1536 - v1535);
    float iqr = p75 - p25;

    if (lane == 0) {
        float* s = sf[w];
        s[4]  = fin(med); s[10] = fin(iqr);
        s[18] = fin(p25); s[19] = fin(p75);
    }
    // Intra-wave LDS visibility: wave is lockstep, only a waitcnt is needed.
    __asm__ volatile("s_waitcnt lgkmcnt(0)" ::: "memory");
    __builtin_amdgcn_sched_barrier(0);

    // ---------------- phase 3: fused MLP (per row) ----------------
    // stage 1: h_j = relu(b1_j + sum_k f_k * W1T[k][j]), lane j in [0,64)
    const float* W1T = wt;            // [20][64]
    const float4* sfv = (const float4*)sf[w];
    float4 f0 = sfv[0], f1 = sfv[1], f2 = sfv[2], f3 = sfv[3], f4 = sfv[4];
    float h = b1[lane];
    h = fmaf(f0.x, W1T[ 0 * 64 + lane], h);
    h = fmaf(f0.y, W1T[ 1 * 64 + lane], h);
    h = fmaf(f0.z, W1T[ 2 * 64 + lane], h);
    h = fmaf(f0.w, W1T[ 3 * 64 + lane], h);
    h = fmaf(f1.x, W1T[ 4 * 64 + lane], h);
    h = fmaf(f1.y, W1T[ 5 * 64 + lane], h);
    h = fmaf(f1.z, W1T[ 6 * 64 + lane], h);
    h = fmaf(f1.w, W1T[ 7 * 64 + lane], h);
    h = fmaf(f2.x, W1T[ 8 * 64 + lane], h);
    h = fmaf(f2.y, W1T[ 9 * 64 + lane], h);
    h = fmaf(f2.z, W1T[10 * 64 + lane], h);
    h = fmaf(f2.w, W1T[11 * 64 + lane], h);
    h = fmaf(f3.x, W1T[12 * 64 + lane], h);
    h = fmaf(f3.y, W1T[13 * 64 + lane], h);
    h = fmaf(f3.z, W1T[14 * 64 + lane], h);
    h = fmaf(f3.w, W1T[15 * 64 + lane], h);
    h = fmaf(f4.x, W1T[16 * 64 + lane], h);
    h = fmaf(f4.y, W1T[17 * 64 + lane], h);
    h = fmaf(f4.z, W1T[18 * 64 + lane], h);
    h = fmaf(f4.w, W1T[19 * 64 + lane], h);
    h = fmaxf(h, 0.f);
    hsh[w][lane] = h;
    __asm__ volatile("s_waitcnt lgkmcnt(0)" ::: "memory");
    __builtin_amdgcn_sched_barrier(0);

    // stage 2: lane j -> outputs 2j, 2j+1 via direct row-major W2 float4 reads
    const int j2 = lane * 2;
    float2 b2v = *(const float2*)(b2 + j2);
    float acc0 = b2v.x, acc1b = b2v.y;
    const float4* w2r0 = (const float4*)(W2 + (size_t)j2 * 64);
    const float4* w2r1 = (const float4*)(W2 + (size_t)(j2 + 1) * 64);
    const float4* hv4 = (const float4*)hsh[w];
    #pragma unroll
    for (int q = 0; q < 16; q++) {
        float4 hq = hv4[q];
        float4 wa = w2r0[q];
        float4 wb = w2r1[q];
        acc0 = fmaf(hq.x, wa.x, acc0); acc1b = fmaf(hq.x, wb.x, acc1b);
        acc0 = fmaf(hq.y, wa.y, acc0); acc1b = fmaf(hq.y, wb.y, acc1b);
        acc0 = fmaf(hq.z, wa.z, acc0); acc1b = fmaf(hq.z, wb.z, acc1b);
        acc0 = fmaf(hq.w, wa.w, acc0); acc1b = fmaf(hq.w, wb.w, acc1b);
    }
    *(float2*)(out + (size_t)gw * 128 + j2) = make_float2(acc0, acc1b);
}

extern "C" void kernel_launch(void* const* d_in, const int* in_sizes, int n_in,
                              void* d_out, int out_size, void* d_ws, size_t ws_size,
                              hipStream_t stream) {
    const float* x  = (const float*)d_in[0];
    const float* W1 = (const float*)d_in[1];
    const float* b1 = (const float*)d_in[2];
    const float* W2 = (const float*)d_in[3];
    const float* b2 = (const float*)d_in[4];
    float* out = (float*)d_out;
    float* wt  = (float*)d_ws;       // 1280 floats: W1T
    int nrows = in_sizes[0] / S_LEN;
    int blocks = (nrows + 3) / 4;    // wave per row
    transpose_w_kernel<<<2, 256, 0, stream>>>(W1, wt);
    fused_stats_mlp_kernel<<<blocks, 256, 0, stream>>>(x, wt, b1, W2, b2, out, nrows);
}

// Round 5
// 266.386 us; speedup vs baseline: 1.0778x; 1.0778x over previous
//
#include <hip/hip_runtime.h>
#include <cmath>

constexpr int S_LEN = 2048;
constexpr float EPS = 1e-8f;

typedef unsigned uvec32 __attribute__((ext_vector_type(32)));

__device__ __forceinline__ float fin(float v) { return isfinite(v) ? v : 0.0f; }
__device__ __forceinline__ float rcpf(float x) { return __builtin_amdgcn_rcpf(x); }

__device__ __forceinline__ unsigned f2o_bits(unsigned u) {
    return (u & 0x80000000u) ? ~u : (u | 0x80000000u);
}
__device__ __forceinline__ float o2f(unsigned u) {
    return __uint_as_float((u & 0x80000000u) ? (u ^ 0x80000000u) : ~u);
}

// ---- DPP helpers (ctrl/rmask are ICEs via template params) ----
template <int Ctrl, int Rmask>
__device__ __forceinline__ int dpp_zero_i(int x) {
    return __builtin_amdgcn_update_dpp(0, x, Ctrl, Rmask, 0xF, true);
}
template <int Ctrl>
__device__ __forceinline__ int dpp_keep_i(int x) {
    return __builtin_amdgcn_update_dpp(x, x, Ctrl, 0xF, 0xF, false);
}
// shfl_down(x,1) across the wave: wave_shl1 (0x130) = dest i <- src i+1,
// bound_ctrl zero-fill -> lane 63 gets 0.
__device__ __forceinline__ float dpp_shdn1_f(float x) {
    return __uint_as_float((unsigned)dpp_zero_i<0x130, 0xF>((int)__float_as_uint(x)));
}
__device__ __forceinline__ int wred_add_i(int v) {
    v += dpp_zero_i<0xB1, 0xF>(v);
    v += dpp_zero_i<0x4E, 0xF>(v);
    v += dpp_zero_i<0x114, 0xF>(v);
    v += dpp_zero_i<0x118, 0xF>(v);
    v += dpp_zero_i<0x142, 0xA>(v);
    v += dpp_zero_i<0x143, 0xC>(v);
    return __builtin_amdgcn_readlane(v, 63);
}
__device__ __forceinline__ float wred_add_f(float v) {
    #define ADDF(CT, RM) v += __uint_as_float((unsigned)dpp_zero_i<CT, RM>((int)__float_as_uint(v)))
    ADDF(0xB1, 0xF); ADDF(0x4E, 0xF); ADDF(0x114, 0xF);
    ADDF(0x118, 0xF); ADDF(0x142, 0xA); ADDF(0x143, 0xC);
    #undef ADDF
    return __uint_as_float((unsigned)__builtin_amdgcn_readlane((int)__float_as_uint(v), 63));
}
__device__ __forceinline__ float wred_min_f(float v) {
    #define MINF(CT) v = fminf(v, __uint_as_float((unsigned)dpp_keep_i<CT>((int)__float_as_uint(v))))
    MINF(0xB1); MINF(0x4E); MINF(0x114); MINF(0x118); MINF(0x142); MINF(0x143);
    #undef MINF
    return __uint_as_float((unsigned)__builtin_amdgcn_readlane((int)__float_as_uint(v), 63));
}
__device__ __forceinline__ float wred_max_f(float v) {
    #define MAXF(CT) v = fmaxf(v, __uint_as_float((unsigned)dpp_keep_i<CT>((int)__float_as_uint(v))))
    MAXF(0xB1); MAXF(0x4E); MAXF(0x114); MAXF(0x118); MAXF(0x142); MAXF(0x143);
    #undef MAXF
    return __uint_as_float((unsigned)__builtin_amdgcn_readlane((int)__float_as_uint(v), 63));
}
__device__ __forceinline__ unsigned wred_umin(unsigned v) {
    #define MINU(CT) { unsigned t = (unsigned)dpp_keep_i<CT>((int)v); v = v < t ? v : t; }
    MINU(0xB1) MINU(0x4E) MINU(0x114) MINU(0x118) MINU(0x142) MINU(0x143)
    #undef MINU
    return (unsigned)__builtin_amdgcn_readlane((int)v, 63);
}
__device__ __forceinline__ float readlane_f(float x, int l) {
    return __uint_as_float((unsigned)__builtin_amdgcn_readlane((int)__float_as_uint(x), l));
}

// Hacker's Delight 32x32 bit transpose (anti-diagonal; involution).
// j=16, j=8 via v_perm_b32 (byte shuffles); j=4,2,1 via bfi masked-merge:
// A' = ((B>>j)&m)|(A&~m);  B' = ((A<<j)&~m)|(B&m)   [note m<<j == ~m here]
__device__ __forceinline__ void transpose32(uvec32& A) {
    #pragma unroll
    for (int k = 0; k < 16; k++) {
        unsigned lo = __builtin_amdgcn_perm(A[k], A[k + 16], 0x07060302u);
        unsigned hi = __builtin_amdgcn_perm(A[k], A[k + 16], 0x05040100u);
        A[k] = lo; A[k + 16] = hi;
    }
    #pragma unroll
    for (int k0 = 0; k0 < 32; k0 += 16) {
        #pragma unroll
        for (int k = k0; k < k0 + 8; k++) {
            unsigned lo = __builtin_amdgcn_perm(A[k], A[k + 8], 0x07030501u);
            unsigned hi = __builtin_amdgcn_perm(A[k], A[k + 8], 0x06020400u);
            A[k] = lo; A[k + 8] = hi;
        }
    }
    #pragma unroll
    for (int j = 4; j; j >>= 1) {
        const unsigned m = (j == 4) ? 0x0F0F0F0Fu : (j == 2) ? 0x33333333u : 0x55555555u;
        #pragma unroll
        for (int k = 0; k < 32; k++) {
            if (!(k & j)) {
                unsigned Ak = A[k], Bk = A[k | j];
                A[k]     = ((Bk >> j) & m) | (Ak & ~m);
                A[k | j] = ((Ak << j) & ~m) | (Bk & m);
            }
        }
    }
}

#define VF(e) __uint_as_float(a[e])

// ============ K0: transpose W1 once into d_ws ============
// wt[0:1280) = W1T (20 x 64): W1T[k*64+j] = W1[j*20+k]
__global__ __launch_bounds__(256) void transpose_w_kernel(
    const float* __restrict__ W1, float* __restrict__ wt)
{
    int tid = blockIdx.x * blockDim.x + threadIdx.x;
    int stride = gridDim.x * blockDim.x;
    for (int n = tid; n < 64 * 20; n += stride) {
        int j = n & 63, k = n >> 6;
        wt[n] = W1[j * 20 + k];
    }
}

// ============ K1: stats + percentiles + fused per-row MLP (wave/row) ============
// feats order (LDS sf slots): 0 mean, 1 std, 2 min, 3 max, 4 median, 5 trend,
// 6 ac1, 7 ac7, 8 ac24, 9 cv, 10 iqr, 11 seasonal, 12 skew, 13 kurt, 14 len,
// 15 sad, 16 madiff, 17 std_diff, 18 p25, 19 p75
__global__ __launch_bounds__(256, 5) void fused_stats_mlp_kernel(
    const float* __restrict__ x, const float* __restrict__ wt,
    const float* __restrict__ b1, const float* __restrict__ W2,
    const float* __restrict__ b2, float* __restrict__ out, int nrows)
{
    __shared__ __align__(16) float sf[4][20];   // per-wave feature stash (wave-uniform)
    __shared__ __align__(16) float hsh[4][64];  // per-wave hidden layer

    const int gw   = (blockIdx.x * 256 + threadIdx.x) >> 6;  // row
    const int lane = threadIdx.x & 63;
    const int w    = (threadIdx.x >> 6);
    if (gw >= nrows) return;

    uvec32 a;
    const float* xr = x + (size_t)gw * S_LEN + lane * 32;
    #pragma unroll
    for (int q = 0; q < 8; q++) {
        float4 t = reinterpret_cast<const float4*>(xr)[q];
        a[4 * q + 0] = __float_as_uint(t.x); a[4 * q + 1] = __float_as_uint(t.y);
        a[4 * q + 2] = __float_as_uint(t.z); a[4 * q + 3] = __float_as_uint(t.w);
    }

    // ---------------- phase 1: streaming stats (raw moments) ----------------
    float s1 = 0.f, s2 = 0.f, s3 = 0.f, s4 = 0.f, sd2 = 0.f, sad = 0.f;
    float p1 = 0.f, p7 = 0.f, p24 = 0.f, se1 = 0.f, se2 = 0.f;
    float mn = VF(0), mx = VF(0);
    #pragma unroll
    for (int e = 0; e < 32; e++) {
        float val = VF(e);
        float t = val * val;
        s1 += val; s2 += t;
        s3 = fmaf(t, val, s3); s4 = fmaf(t, t, s4);
        mn = fminf(mn, val); mx = fmaxf(mx, val);
    }
    #pragma unroll
    for (int e = 0; e < 31; e++) {
        float d = VF(e + 1) - VF(e);
        sd2 = fmaf(d, d, sd2); sad += fabsf(d);
        p1 = fmaf(VF(e), VF(e + 1), p1);
    }
    #pragma unroll
    for (int e = 0; e < 25; e++) p7 = fmaf(VF(e), VF(e + 7), p7);
    #pragma unroll
    for (int e = 0; e < 8; e++)  p24 = fmaf(VF(e), VF(e + 24), p24);

    const bool notlast = (lane < 63);
    #pragma unroll
    for (int j = 0; j < 24; j++) {
        float g = dpp_shdn1_f(VF(j));          // lane 63 -> 0
        p24 = fmaf(VF(8 + j), g, p24);
        if (j < 7) p7 = fmaf(VF(25 + j), g, p7);
        if (j == 0) {
            float d = g - VF(31);
            float dm = notlast ? d : 0.f;
            sd2 = fmaf(dm, dm, sd2); sad += fabsf(dm);
            p1 = fmaf(VF(31), g, p1);
        }
    }
    {   // seasonal x[::24]
        int r3 = lane % 3;
        float sv = (r3 == 0) ? VF(0) : ((r3 == 1) ? VF(16) : VF(8));
        se1 += sv; se2 = fmaf(sv, sv, se2);
        if (r3 == 0) { se1 += VF(24); se2 = fmaf(VF(24), VF(24), se2); }
    }
    // head (lane 0 forward) and tail (lane 63 reversed) partials in one loop
    const bool is63 = (lane == 63);
    float acc1 = 0.f, acc2 = 0.f, ck1 = 0.f, ck2 = 0.f;
    #pragma unroll
    for (int i = 0; i < 24; i++) {
        float pick = is63 ? VF(31 - i) : VF(i);
        acc1 += pick; acc2 = fmaf(pick, pick, acc2);
        if (i == 6) { ck1 = acc1; ck2 = acc2; }
    }
    const float h1  = readlane_f(VF(0), 0),   t1  = readlane_f(VF(31), 63);
    const float h7  = readlane_f(ck1, 0),     hq7 = readlane_f(ck2, 0);
    const float h24 = readlane_f(acc1, 0),    hq24 = readlane_f(acc2, 0);
    const float t7  = readlane_f(ck1, 63),    tq7 = readlane_f(ck2, 63);
    const float t24 = readlane_f(acc1, 63),   tq24 = readlane_f(acc2, 63);
    const float hq1 = h1 * h1, tq1 = t1 * t1;

    float S1  = wred_add_f(s1);
    float S2  = wred_add_f(s2);
    float S3  = wred_add_f(s3);
    float S4  = wred_add_f(s4);
    float SD2 = wred_add_f(sd2);
    float SAD = wred_add_f(sad);
    float P1  = wred_add_f(p1);
    float P7  = wred_add_f(p7);
    float P24 = wred_add_f(p24);
    float SE1 = wred_add_f(se1);
    float SE2 = wred_add_f(se2);
    float MN  = wred_min_f(mn);
    float MX  = wred_max_f(mx);

    // 16 stat features -> LDS stash NOW (frees registers across the select)
    {
        constexpr float invS  = 1.0f / 2048.0f;   // exact (pow2)
        constexpr float invND = 1.0f / 2047.0f;
        const float Sf = (float)S_LEN;
        float mu = S1 * invS;
        float q2 = S2 * invS, q3 = S3 * invS, q4 = S4 * invS;
        float mu2 = mu * mu;
        float m2v = q2 - mu2;
        float m3v = q3 - 3.f * mu * q2 + 2.f * mu * mu2;
        float m4v = q4 - 4.f * mu * q3 + 6.f * mu2 * q2 - 3.f * mu2 * mu2;
        float stdv = sqrtf(m2v);
        float dmean = (t1 - h1) * invND;
        float dvar = SD2 * invND - dmean * dmean;
        float std_diff = sqrtf(fmaxf(dvar, 0.f));
        float trend = std_diff * rcpf(stdv + EPS);
        float ac[3];
        const float invN[3] = {1.0f / 2047.0f, 1.0f / 2041.0f, 1.0f / 2024.0f};
        const float Ps[3] = {P1, P7, P24};
        const float hd[3] = {h1, h7, h24},   hqv[3] = {hq1, hq7, hq24};
        const float tl[3] = {t1, t7, t24},   tqv[3] = {tq1, tq7, tq24};
        #pragma unroll
        for (int q = 0; q < 3; q++) {
            float in = invN[q];
            float sa = S1 - tl[q], sb = S1 - hd[q];
            float qa = S2 - tqv[q], qb = S2 - hqv[q];
            float am = sa * in, bm = sb * in;
            float cov = Ps[q] * in - am * bm;
            float as_ = sqrtf(fmaxf(qa * in - am * am, 0.f));
            float bs_ = sqrtf(fmaxf(qb * in - bm * bm, 0.f));
            ac[q] = cov * rcpf(as_ * bs_);
        }
        float cv = stdv * rcpf(fabsf(mu) + EPS);
        float sm = SE1 * (1.0f / 86.0f);
        float svar = SE2 * (1.0f / 86.0f) - sm * sm;
        float seasonal = svar * rcpf(m2v + EPS);
        float skew = m3v * rcpf(m2v * stdv);
        float kurt = m4v * rcpf(m2v * m2v) - 3.f;
        if (lane == 0) {
            float* s = sf[w];
            s[0]  = fin(mu);       s[1]  = fin(stdv);
            s[2]  = fin(MN);       s[3]  = fin(MX);
            s[5]  = fin(trend);    s[6]  = fin(ac[0]);
            s[7]  = fin(ac[1]);    s[8]  = fin(ac[2]);
            s[9]  = fin(cv);       s[11] = fin(seasonal);
            s[12] = fin(skew);     s[13] = fin(kurt);
            s[14] = Sf;            s[15] = fin(SAD);
            s[16] = fin(SAD * invND); s[17] = fin(std_diff);
        }
    }

    // ---------------- phase 2: bit-plane radix select ----------------
    #pragma unroll
    for (int e = 0; e < 32; e++) a[e] = f2o_bits(a[e]);
    transpose32(a);

    // Count ONES (w = act & plane); zeros = cnt - ones; cnt tracked in scalars.
    unsigned act0 = ~0u, act1 = ~0u, act2 = ~0u;
    int K0 = 511, K1 = 1023, K2 = 1535;
    int cnt0 = 2048, cnt1 = 2048, cnt2 = 2048;
    unsigned uK0 = 0, uK1 = 0, uK2 = 0;
    #pragma unroll
    for (int b = 31; b >= 0; b--) {
        unsigned mb = a[31 - b];
        unsigned w0 = act0 & mb, w1 = act1 & mb, w2 = act2 & mb;
        int O01 = wred_add_i(__popc(w0) | (__popc(w1) << 16));
        int O2  = wred_add_i(__popc(w2));
        int c0 = cnt0 - (O01 & 0xFFFF);
        int c1 = cnt1 - (int)((unsigned)O01 >> 16);
        int c2i = cnt2 - O2;
        // branch-free selects (uniform conditions)
        bool t0 = (K0 >= c0), t1c = (K1 >= c1), t2c = (K2 >= c2i);
        act0 = t0  ? w0 : (act0 ^ w0);
        act1 = t1c ? w1 : (act1 ^ w1);
        act2 = t2c ? w2 : (act2 ^ w2);
        cnt0 = t0  ? (cnt0 - c0)  : c0;
        cnt1 = t1c ? (cnt1 - c1)  : c1;
        cnt2 = t2c ? (cnt2 - c2i) : c2i;
        K0 = t0  ? (K0 - c0)  : K0;
        K1 = t1c ? (K1 - c1)  : K1;
        K2 = t2c ? (K2 - c2i) : K2;
        uK0 |= t0  ? (1u << b) : 0u;
        uK1 |= t1c ? (1u << b) : 0u;
        uK2 |= t2c ? (1u << b) : 0u;
    }
    // After bit 0, act marks exactly the elements equal to uK: eq == cnt.
    const int eq0 = cnt0, eq1 = cnt1, eq2 = cnt2;

    transpose32(a);  // involution -> recover orderable values
    // min over {ue > uK} via wrap-around: ue - (uK+1) is small iff ue > uK.
    const unsigned k0p1 = uK0 + 1, k1p1 = uK1 + 1, k2p1 = uK2 + 1;
    unsigned m0 = ~0u, m1 = ~0u, m2 = ~0u;
    #pragma unroll
    for (int e = 0; e < 32; e++) {
        unsigned ue = a[e];
        unsigned d0 = ue - k0p1; m0 = m0 < d0 ? m0 : d0;
        unsigned d1 = ue - k1p1; m1 = m1 < d1 ? m1 : d1;
        unsigned d2 = ue - k2p1; m2 = m2 < d2 ? m2 : d2;
    }
    m0 = wred_umin(m0) + k0p1;
    m1 = wred_umin(m1) + k1p1;
    m2 = wred_umin(m2) + k2p1;

    float v511 = o2f(uK0), v1023 = o2f(uK1), v1535 = o2f(uK2);
    float v512  = (K0 + 1 < eq0) ? v511  : o2f(m0);
    float v1024 = (K1 + 1 < eq1) ? v1023 : o2f(m1);
    float v1536 = (K2 + 1 < eq2) ? v1535 : o2f(m2);
    float p25 = v511 + 0.75f * (v512 - v511);
    float med = 0.5f * (v1023 + v1024);
    float p75 = v1535 + 0.25f * (v1536 - v1535);
    float iqr = p75 - p25;

    if (lane == 0) {
        float* s = sf[w];
        s[4]  = fin(med); s[10] = fin(iqr);
        s[18] = fin(p25); s[19] = fin(p75);
    }
    // Intra-wave LDS visibility: wave is lockstep, only a waitcnt is needed.
    __asm__ volatile("s_waitcnt lgkmcnt(0)" ::: "memory");
    __builtin_amdgcn_sched_barrier(0);

    // ---------------- phase 3: fused MLP (per row) ----------------
    // stage 1: h_j = relu(b1_j + sum_k f_k * W1T[k][j]), lane j in [0,64)
    const float* W1T = wt;            // [20][64]
    const float4* sfv = (const float4*)sf[w];
    float4 f0 = sfv[0], f1 = sfv[1], f2 = sfv[2], f3 = sfv[3], f4 = sfv[4];
    float h = b1[lane];
    h = fmaf(f0.x, W1T[ 0 * 64 + lane], h);
    h = fmaf(f0.y, W1T[ 1 * 64 + lane], h);
    h = fmaf(f0.z, W1T[ 2 * 64 + lane], h);
    h = fmaf(f0.w, W1T[ 3 * 64 + lane], h);
    h = fmaf(f1.x, W1T[ 4 * 64 + lane], h);
    h = fmaf(f1.y, W1T[ 5 * 64 + lane], h);
    h = fmaf(f1.z, W1T[ 6 * 64 + lane], h);
    h = fmaf(f1.w, W1T[ 7 * 64 + lane], h);
    h = fmaf(f2.x, W1T[ 8 * 64 + lane], h);
    h = fmaf(f2.y, W1T[ 9 * 64 + lane], h);
    h = fmaf(f2.z, W1T[10 * 64 + lane], h);
    h = fmaf(f2.w, W1T[11 * 64 + lane], h);
    h = fmaf(f3.x, W1T[12 * 64 + lane], h);
    h = fmaf(f3.y, W1T[13 * 64 + lane], h);
    h = fmaf(f3.z, W1T[14 * 64 + lane], h);
    h = fmaf(f3.w, W1T[15 * 64 + lane], h);
    h = fmaf(f4.x, W1T[16 * 64 + lane], h);
    h = fmaf(f4.y, W1T[17 * 64 + lane], h);
    h = fmaf(f4.z, W1T[18 * 64 + lane], h);
    h = fmaf(f4.w, W1T[19 * 64 + lane], h);
    h = fmaxf(h, 0.f);
    hsh[w][lane] = h;
    __asm__ volatile("s_waitcnt lgkmcnt(0)" ::: "memory");
    __builtin_amdgcn_sched_barrier(0);

    // stage 2: lane j -> outputs 2j, 2j+1 via direct row-major W2 float4 reads
    const int j2 = lane * 2;
    float2 b2v = *(const float2*)(b2 + j2);
    float acc0 = b2v.x, acc1b = b2v.y;
    const float4* w2r0 = (const float4*)(W2 + (size_t)j2 * 64);
    const float4* w2r1 = (const float4*)(W2 + (size_t)(j2 + 1) * 64);
    const float4* hv4 = (const float4*)hsh[w];
    #pragma unroll
    for (int q = 0; q < 16; q++) {
        float4 hq = hv4[q];
        float4 wa = w2r0[q];
        float4 wb = w2r1[q];
        acc0 = fmaf(hq.x, wa.x, acc0); acc1b = fmaf(hq.x, wb.x, acc1b);
        acc0 = fmaf(hq.y, wa.y, acc0); acc1b = fmaf(hq.y, wb.y, acc1b);
        acc0 = fmaf(hq.z, wa.z, acc0); acc1b = fmaf(hq.z, wb.z, acc1b);
        acc0 = fmaf(hq.w, wa.w, acc0); acc1b = fmaf(hq.w, wb.w, acc1b);
    }
    *(float2*)(out + (size_t)gw * 128 + j2) = make_float2(acc0, acc1b);
}

extern "C" void kernel_launch(void* const* d_in, const int* in_sizes, int n_in,
                              void* d_out, int out_size, void* d_ws, size_t ws_size,
                              hipStream_t stream) {
    const float* x  = (const float*)d_in[0];
    const float* W1 = (const float*)d_in[1];
    const float* b1 = (const float*)d_in[2];
    const float* W2 = (const float*)d_in[3];
    const float* b2 = (const float*)d_in[4];
    float* out = (float*)d_out;
    float* wt  = (float*)d_ws;       // 1280 floats: W1T
    int nrows = in_sizes[0] / S_LEN;
    int blocks = (nrows + 3) / 4;    // wave per row
    transpose_w_kernel<<<2, 256, 0, stream>>>(W1, wt);
    fused_stats_mlp_kernel<<<blocks, 256, 0, stream>>>(x, wt, b1, W2, b2, out, nrows);
}

// Round 7
// 264.519 us; speedup vs baseline: 1.0854x; 1.0071x over previous
//
#include <hip/hip_runtime.h>
#include <cmath>

constexpr int S_LEN = 2048;
constexpr float EPS = 1e-8f;

typedef unsigned uvec32 __attribute__((ext_vector_type(32)));

__device__ __forceinline__ float fin(float v) { return isfinite(v) ? v : 0.0f; }
__device__ __forceinline__ float rcpf(float x) { return __builtin_amdgcn_rcpf(x); }

__device__ __forceinline__ unsigned f2o_bits(unsigned u) {
    return (u & 0x80000000u) ? ~u : (u | 0x80000000u);
}
__device__ __forceinline__ float o2f(unsigned u) {
    return __uint_as_float((u & 0x80000000u) ? (u ^ 0x80000000u) : ~u);
}

// ---- DPP helpers (ctrl/rmask are ICEs via template params) ----
template <int Ctrl, int Rmask>
__device__ __forceinline__ int dpp_zero_i(int x) {
    return __builtin_amdgcn_update_dpp(0, x, Ctrl, Rmask, 0xF, true);
}
template <int Ctrl>
__device__ __forceinline__ int dpp_keep_i(int x) {
    return __builtin_amdgcn_update_dpp(x, x, Ctrl, 0xF, 0xF, false);
}
// shfl_down(x,1) across the wave: wave_shl1 (0x130) = dest i <- src i+1,
// bound_ctrl zero-fill -> lane 63 gets 0.
__device__ __forceinline__ float dpp_shdn1_f(float x) {
    return __uint_as_float((unsigned)dpp_zero_i<0x130, 0xF>((int)__float_as_uint(x)));
}
__device__ __forceinline__ int wred_add_i(int v) {
    v += dpp_zero_i<0xB1, 0xF>(v);
    v += dpp_zero_i<0x4E, 0xF>(v);
    v += dpp_zero_i<0x114, 0xF>(v);
    v += dpp_zero_i<0x118, 0xF>(v);
    v += dpp_zero_i<0x142, 0xA>(v);
    v += dpp_zero_i<0x143, 0xC>(v);
    return __builtin_amdgcn_readlane(v, 63);
}
__device__ __forceinline__ float wred_add_f(float v) {
    #define ADDF(CT, RM) v += __uint_as_float((unsigned)dpp_zero_i<CT, RM>((int)__float_as_uint(v)))
    ADDF(0xB1, 0xF); ADDF(0x4E, 0xF); ADDF(0x114, 0xF);
    ADDF(0x118, 0xF); ADDF(0x142, 0xA); ADDF(0x143, 0xC);
    #undef ADDF
    return __uint_as_float((unsigned)__builtin_amdgcn_readlane((int)__float_as_uint(v), 63));
}
__device__ __forceinline__ float wred_min_f(float v) {
    #define MINF(CT) v = fminf(v, __uint_as_float((unsigned)dpp_keep_i<CT>((int)__float_as_uint(v))))
    MINF(0xB1); MINF(0x4E); MINF(0x114); MINF(0x118); MINF(0x142); MINF(0x143);
    #undef MINF
    return __uint_as_float((unsigned)__builtin_amdgcn_readlane((int)__float_as_uint(v), 63));
}
__device__ __forceinline__ float wred_max_f(float v) {
    #define MAXF(CT) v = fmaxf(v, __uint_as_float((unsigned)dpp_keep_i<CT>((int)__float_as_uint(v))))
    MAXF(0xB1); MAXF(0x4E); MAXF(0x114); MAXF(0x118); MAXF(0x142); MAXF(0x143);
    #undef MAXF
    return __uint_as_float((unsigned)__builtin_amdgcn_readlane((int)__float_as_uint(v), 63));
}
__device__ __forceinline__ unsigned wred_umin(unsigned v) {
    #define MINU(CT) { unsigned t = (unsigned)dpp_keep_i<CT>((int)v); v = v < t ? v : t; }
    MINU(0xB1) MINU(0x4E) MINU(0x114) MINU(0x118) MINU(0x142) MINU(0x143)
    #undef MINU
    return (unsigned)__builtin_amdgcn_readlane((int)v, 63);
}
__device__ __forceinline__ float readlane_f(float x, int l) {
    return __uint_as_float((unsigned)__builtin_amdgcn_readlane((int)__float_as_uint(x), l));
}

// Hacker's Delight 32x32 bit transpose (anti-diagonal; involution).
// j=16, j=8 via v_perm_b32 (byte shuffles); j=4,2,1 via masked-merge:
// A' = ((B>>j)&m)|(A&~m);  B' = ((A<<j)&~m)|(B&m)   [note m<<j == ~m here]
__device__ __forceinline__ void transpose32(uvec32& A) {
    #pragma unroll
    for (int k = 0; k < 16; k++) {
        unsigned lo = __builtin_amdgcn_perm(A[k], A[k + 16], 0x07060302u);
        unsigned hi = __builtin_amdgcn_perm(A[k], A[k + 16], 0x05040100u);
        A[k] = lo; A[k + 16] = hi;
    }
    #pragma unroll
    for (int k0 = 0; k0 < 32; k0 += 16) {
        #pragma unroll
        for (int k = k0; k < k0 + 8; k++) {
            unsigned lo = __builtin_amdgcn_perm(A[k], A[k + 8], 0x07030501u);
            unsigned hi = __builtin_amdgcn_perm(A[k], A[k + 8], 0x06020400u);
            A[k] = lo; A[k + 8] = hi;
        }
    }
    #pragma unroll
    for (int j = 4; j; j >>= 1) {
        const unsigned m = (j == 4) ? 0x0F0F0F0Fu : (j == 2) ? 0x33333333u : 0x55555555u;
        #pragma unroll
        for (int k = 0; k < 32; k++) {
            if (!(k & j)) {
                unsigned Ak = A[k], Bk = A[k | j];
                A[k]     = ((Bk >> j) & m) | (Ak & ~m);
                A[k | j] = ((Ak << j) & ~m) | (Bk & m);
            }
        }
    }
}

#define VF(e) __uint_as_float(a[e])

// ============ K0: transpose W1 once into d_ws ============
// wt[0:1280) = W1T (20 x 64): W1T[k*64+j] = W1[j*20+k]
__global__ __launch_bounds__(256) void transpose_w_kernel(
    const float* __restrict__ W1, float* __restrict__ wt)
{
    int tid = blockIdx.x * blockDim.x + threadIdx.x;
    int stride = gridDim.x * blockDim.x;
    for (int n = tid; n < 64 * 20; n += stride) {
        int j = n & 63, k = n >> 6;
        wt[n] = W1[j * 20 + k];
    }
}

// ============ K1: stats + percentiles + fused per-row MLP (wave/row) ============
// feats order (LDS sf slots): 0 mean, 1 std, 2 min, 3 max, 4 median, 5 trend,
// 6 ac1, 7 ac7, 8 ac24, 9 cv, 10 iqr, 11 seasonal, 12 skew, 13 kurt, 14 len,
// 15 sad, 16 madiff, 17 std_diff, 18 p25, 19 p75
__global__ __launch_bounds__(256, 5) void fused_stats_mlp_kernel(
    const float* __restrict__ x, const float* __restrict__ wt,
    const float* __restrict__ b1, const float* __restrict__ W2,
    const float* __restrict__ b2, float* __restrict__ out, int nrows)
{
    __shared__ __align__(16) float sf[4][20];   // per-wave feature stash (wave-uniform)
    __shared__ __align__(16) float hsh[4][64];  // per-wave hidden layer

    const int gw   = (blockIdx.x * 256 + threadIdx.x) >> 6;  // row
    const int lane = threadIdx.x & 63;
    const int w    = (threadIdx.x >> 6);
    if (gw >= nrows) return;

    uvec32 a;
    const float* xr = x + (size_t)gw * S_LEN + lane * 32;
    #pragma unroll
    for (int q = 0; q < 8; q++) {
        float4 t = reinterpret_cast<const float4*>(xr)[q];
        a[4 * q + 0] = __float_as_uint(t.x); a[4 * q + 1] = __float_as_uint(t.y);
        a[4 * q + 2] = __float_as_uint(t.z); a[4 * q + 3] = __float_as_uint(t.w);
    }

    // ---------------- phase 1: streaming stats (raw moments) ----------------
    float s1 = 0.f, s2 = 0.f, s3 = 0.f, s4 = 0.f, sd2 = 0.f, sad = 0.f;
    float p1 = 0.f, p7 = 0.f, p24 = 0.f, se1 = 0.f, se2 = 0.f;
    float mn = VF(0), mx = VF(0);
    #pragma unroll
    for (int e = 0; e < 32; e++) {
        float val = VF(e);
        float t = val * val;
        s1 += val; s2 += t;
        s3 = fmaf(t, val, s3); s4 = fmaf(t, t, s4);
        mn = fminf(mn, val); mx = fmaxf(mx, val);
    }
    #pragma unroll
    for (int e = 0; e < 31; e++) {
        float d = VF(e + 1) - VF(e);
        sd2 = fmaf(d, d, sd2); sad += fabsf(d);
        p1 = fmaf(VF(e), VF(e + 1), p1);
    }
    #pragma unroll
    for (int e = 0; e < 25; e++) p7 = fmaf(VF(e), VF(e + 7), p7);
    #pragma unroll
    for (int e = 0; e < 8; e++)  p24 = fmaf(VF(e), VF(e + 24), p24);

    const bool notlast = (lane < 63);
    #pragma unroll
    for (int j = 0; j < 24; j++) {
        float g = dpp_shdn1_f(VF(j));          // lane 63 -> 0
        p24 = fmaf(VF(8 + j), g, p24);
        if (j < 7) p7 = fmaf(VF(25 + j), g, p7);
        if (j == 0) {
            float d = g - VF(31);
            float dm = notlast ? d : 0.f;
            sd2 = fmaf(dm, dm, sd2); sad += fabsf(dm);
            p1 = fmaf(VF(31), g, p1);
        }
    }
    {   // seasonal x[::24]
        int r3 = lane % 3;
        float sv = (r3 == 0) ? VF(0) : ((r3 == 1) ? VF(16) : VF(8));
        se1 += sv; se2 = fmaf(sv, sv, se2);
        if (r3 == 0) { se1 += VF(24); se2 = fmaf(VF(24), VF(24), se2); }
    }
    // head (lane 0 forward) and tail (lane 63 reversed) partials in one loop
    const bool is63 = (lane == 63);
    float acc1 = 0.f, acc2 = 0.f, ck1 = 0.f, ck2 = 0.f;
    #pragma unroll
    for (int i = 0; i < 24; i++) {
        float pick = is63 ? VF(31 - i) : VF(i);
        acc1 += pick; acc2 = fmaf(pick, pick, acc2);
        if (i == 6) { ck1 = acc1; ck2 = acc2; }
    }
    const float h1  = readlane_f(VF(0), 0),   t1  = readlane_f(VF(31), 63);
    const float h7  = readlane_f(ck1, 0),     hq7 = readlane_f(ck2, 0);
    const float h24 = readlane_f(acc1, 0),    hq24 = readlane_f(acc2, 0);
    const float t7  = readlane_f(ck1, 63),    tq7 = readlane_f(ck2, 63);
    const float t24 = readlane_f(acc1, 63),   tq24 = readlane_f(acc2, 63);
    const float hq1 = h1 * h1, tq1 = t1 * t1;

    float S1  = wred_add_f(s1);
    float S2  = wred_add_f(s2);
    float S3  = wred_add_f(s3);
    float S4  = wred_add_f(s4);
    float SD2 = wred_add_f(sd2);
    float SAD = wred_add_f(sad);
    float P1  = wred_add_f(p1);
    float P7  = wred_add_f(p7);
    float P24 = wred_add_f(p24);
    float SE1 = wred_add_f(se1);
    float SE2 = wred_add_f(se2);
    float MN  = wred_min_f(mn);
    float MX  = wred_max_f(mx);

    // 16 stat features -> LDS stash NOW (frees registers across the select)
    {
        constexpr float invS  = 1.0f / 2048.0f;   // exact (pow2)
        constexpr float invND = 1.0f / 2047.0f;
        const float Sf = (float)S_LEN;
        float mu = S1 * invS;
        float q2 = S2 * invS, q3 = S3 * invS, q4 = S4 * invS;
        float mu2 = mu * mu;
        float m2v = q2 - mu2;
        float m3v = q3 - 3.f * mu * q2 + 2.f * mu * mu2;
        float m4v = q4 - 4.f * mu * q3 + 6.f * mu2 * q2 - 3.f * mu2 * mu2;
        float stdv = sqrtf(m2v);
        float dmean = (t1 - h1) * invND;
        float dvar = SD2 * invND - dmean * dmean;
        float std_diff = sqrtf(fmaxf(dvar, 0.f));
        float trend = std_diff * rcpf(stdv + EPS);
        float ac[3];
        const float invN[3] = {1.0f / 2047.0f, 1.0f / 2041.0f, 1.0f / 2024.0f};
        const float Ps[3] = {P1, P7, P24};
        const float hd[3] = {h1, h7, h24},   hqv[3] = {hq1, hq7, hq24};
        const float tl[3] = {t1, t7, t24},   tqv[3] = {tq1, tq7, tq24};
        #pragma unroll
        for (int q = 0; q < 3; q++) {
            float in = invN[q];
            float sa = S1 - tl[q], sb = S1 - hd[q];
            float qa = S2 - tqv[q], qb = S2 - hqv[q];
            float am = sa * in, bm = sb * in;
            float cov = Ps[q] * in - am * bm;
            float as_ = sqrtf(fmaxf(qa * in - am * am, 0.f));
            float bs_ = sqrtf(fmaxf(qb * in - bm * bm, 0.f));
            ac[q] = cov * rcpf(as_ * bs_);
        }
        float cv = stdv * rcpf(fabsf(mu) + EPS);
        float sm = SE1 * (1.0f / 86.0f);
        float svar = SE2 * (1.0f / 86.0f) - sm * sm;
        float seasonal = svar * rcpf(m2v + EPS);
        float skew = m3v * rcpf(m2v * stdv);
        float kurt = m4v * rcpf(m2v * m2v) - 3.f;
        if (lane == 0) {
            float* s = sf[w];
            s[0]  = fin(mu);       s[1]  = fin(stdv);
            s[2]  = fin(MN);       s[3]  = fin(MX);
            s[5]  = fin(trend);    s[6]  = fin(ac[0]);
            s[7]  = fin(ac[1]);    s[8]  = fin(ac[2]);
            s[9]  = fin(cv);       s[11] = fin(seasonal);
            s[12] = fin(skew);     s[13] = fin(kurt);
            s[14] = Sf;            s[15] = fin(SAD);
            s[16] = fin(SAD * invND); s[17] = fin(std_diff);
        }
    }

    // ---------------- phase 2: bit-plane radix select (early-exit) ----------------
    #pragma unroll
    for (int e = 0; e < 32; e++) a[e] = f2o_bits(a[e]);
    transpose32(a);

    // Count ONES (w = act & plane); zeros = cnt - ones; cnt tracked in scalars.
    // Early exit: all radix state is wave-uniform (flows through readlane63), so
    // once every active set is a single element, remaining bits are recovered
    // after the loop by survivor = min{ue >= uK_prefix} (uniqueness proof: any
    // ue in [uK_prefix, survivor) shares the decided prefix => active => contra).
    unsigned act0 = ~0u, act1 = ~0u, act2 = ~0u;
    int K0 = 511, K1 = 1023, K2 = 1535;
    int cnt0 = 2048, cnt1 = 2048, cnt2 = 2048;
    unsigned uK0 = 0, uK1 = 0, uK2 = 0;
    bool alldone = false;
    #pragma unroll
    for (int b = 31; b >= 0; b--) {
        if (!alldone) {
            unsigned mb = a[31 - b];
            unsigned w0 = act0 & mb, w1 = act1 & mb, w2 = act2 & mb;
            int O01 = wred_add_i(__popc(w0) | (__popc(w1) << 16));
            int O2  = wred_add_i(__popc(w2));
            int c0 = cnt0 - (O01 & 0xFFFF);
            int c1 = cnt1 - (int)((unsigned)O01 >> 16);
            int c2i = cnt2 - O2;
            bool t0 = (K0 >= c0), t1c = (K1 >= c1), t2c = (K2 >= c2i);
            act0 = t0  ? w0 : (act0 ^ w0);
            act1 = t1c ? w1 : (act1 ^ w1);
            act2 = t2c ? w2 : (act2 ^ w2);
            cnt0 = t0  ? (cnt0 - c0)  : c0;
            cnt1 = t1c ? (cnt1 - c1)  : c1;
            cnt2 = t2c ? (cnt2 - c2i) : c2i;
            K0 = t0  ? (K0 - c0)  : K0;
            K1 = t1c ? (K1 - c1)  : K1;
            K2 = t2c ? (K2 - c2i) : K2;
            uK0 |= t0  ? (1u << b) : 0u;
            uK1 |= t1c ? (1u << b) : 0u;
            uK2 |= t2c ? (1u << b) : 0u;
            alldone = (cnt0 == 1) && (cnt1 == 1) && (cnt2 == 1);
        }
    }
    // act marks the elements matching the decided prefix: eq == cnt.
    // (early exit => cnt==1 => eq=1, K=0; full run => cnt = #elements equal uK)
    const int eq0 = cnt0, eq1 = cnt1, eq2 = cnt2;

    transpose32(a);  // involution -> recover orderable values

    // survivor_j = min{ue >= uK_j_prefix} via wrap-around (full run: min d = 0)
    {
        unsigned d0m = ~0u, d1m = ~0u, d2m = ~0u;
        #pragma unroll
        for (int e = 0; e < 32; e++) {
            unsigned ue = a[e];
            unsigned d0 = ue - uK0; d0m = d0m < d0 ? d0m : d0;
            unsigned d1 = ue - uK1; d1m = d1m < d1 ? d1m : d1;
            unsigned d2 = ue - uK2; d2m = d2m < d2 ? d2m : d2;
        }
        uK0 += wred_umin(d0m);
        uK1 += wred_umin(d1m);
        uK2 += wred_umin(d2m);
    }

    // successor_j = min{ue > uK_j} via wrap-around
    const unsigned k0p1 = uK0 + 1, k1p1 = uK1 + 1, k2p1 = uK2 + 1;
    unsigned m0 = ~0u, m1 = ~0u, m2 = ~0u;
    #pragma unroll
    for (int e = 0; e < 32; e++) {
        unsigned ue = a[e];
        unsigned d0 = ue - k0p1; m0 = m0 < d0 ? m0 : d0;
        unsigned d1 = ue - k1p1; m1 = m1 < d1 ? m1 : d1;
        unsigned d2 = ue - k2p1; m2 = m2 < d2 ? m2 : d2;
    }
    m0 = wred_umin(m0) + k0p1;
    m1 = wred_umin(m1) + k1p1;
    m2 = wred_umin(m2) + k2p1;

    float v511 = o2f(uK0), v1023 = o2f(uK1), v1535 = o2f(uK2);
    float v512  = (K0 + 1 < eq0) ? v511  : o2f(m0);
    float v1024 = (K1 + 1 < eq1) ? v1023 : o2f(m1);
    float v1536 = (K2 + 1 < eq2) ? v1535 : o2f(m2);
    float p25 = v511 + 0.75f * (v512 - v511);
    float med = 0.5f * (v1023 + v1024);
    float p75 = v1535 + 0.25f * (v1536 - v1535);
    float iqr = p75 - p25;

    if (lane == 0) {
        float* s = sf[w];
        s[4]  = fin(med); s[10] = fin(iqr);
        s[18] = fin(p25); s[19] = fin(p75);
    }
    // Intra-wave LDS visibility: wave is lockstep, only a waitcnt is needed.
    __asm__ volatile("s_waitcnt lgkmcnt(0)" ::: "memory");
    __builtin_amdgcn_sched_barrier(0);

    // ---------------- phase 3: fused MLP (per row) ----------------
    // stage 1: h_j = relu(b1_j + sum_k f_k * W1T[k][j]), lane j in [0,64)
    const float* W1T = wt;            // [20][64]
    const float4* sfv = (const float4*)sf[w];
    float4 f0 = sfv[0], f1 = sfv[1], f2 = sfv[2], f3 = sfv[3], f4 = sfv[4];
    float h = b1[lane];
    h = fmaf(f0.x, W1T[ 0 * 64 + lane], h);
    h = fmaf(f0.y, W1T[ 1 * 64 + lane], h);
    h = fmaf(f0.z, W1T[ 2 * 64 + lane], h);
    h = fmaf(f0.w, W1T[ 3 * 64 + lane], h);
    h = fmaf(f1.x, W1T[ 4 * 64 + lane], h);
    h = fmaf(f1.y, W1T[ 5 * 64 + lane], h);
    h = fmaf(f1.z, W1T[ 6 * 64 + lane], h);
    h = fmaf(f1.w, W1T[ 7 * 64 + lane], h);
    h = fmaf(f2.x, W1T[ 8 * 64 + lane], h);
    h = fmaf(f2.y, W1T[ 9 * 64 + lane], h);
    h = fmaf(f2.z, W1T[10 * 64 + lane], h);
    h = fmaf(f2.w, W1T[11 * 64 + lane], h);
    h = fmaf(f3.x, W1T[12 * 64 + lane], h);
    h = fmaf(f3.y, W1T[13 * 64 + lane], h);
    h = fmaf(f3.z, W1T[14 * 64 + lane], h);
    h = fmaf(f3.w, W1T[15 * 64 + lane], h);
    h = fmaf(f4.x, W1T[16 * 64 + lane], h);
    h = fmaf(f4.y, W1T[17 * 64 + lane], h);
    h = fmaf(f4.z, W1T[18 * 64 + lane], h);
    h = fmaf(f4.w, W1T[19 * 64 + lane], h);
    h = fmaxf(h, 0.f);
    hsh[w][lane] = h;
    __asm__ volatile("s_waitcnt lgkmcnt(0)" ::: "memory");
    __builtin_amdgcn_sched_barrier(0);

    // stage 2: lane j -> outputs 2j, 2j+1 via direct row-major W2 float4 reads
    const int j2 = lane * 2;
    float2 b2v = *(const float2*)(b2 + j2);
    float acc0 = b2v.x, acc1b = b2v.y;
    const float4* w2r0 = (const float4*)(W2 + (size_t)j2 * 64);
    const float4* w2r1 = (const float4*)(W2 + (size_t)(j2 + 1) * 64);
    const float4* hv4 = (const float4*)hsh[w];
    #pragma unroll
    for (int q = 0; q < 16; q++) {
        float4 hq = hv4[q];
        float4 wa = w2r0[q];
        float4 wb = w2r1[q];
        acc0 = fmaf(hq.x, wa.x, acc0); acc1b = fmaf(hq.x, wb.x, acc1b);
        acc0 = fmaf(hq.y, wa.y, acc0); acc1b = fmaf(hq.y, wb.y, acc1b);
        acc0 = fmaf(hq.z, wa.z, acc0); acc1b = fmaf(hq.z, wb.z, acc1b);
        acc0 = fmaf(hq.w, wa.w, acc0); acc1b = fmaf(hq.w, wb.w, acc1b);
    }
    *(float2*)(out + (size_t)gw * 128 + j2) = make_float2(acc0, acc1b);
}

extern "C" void kernel_launch(void* const* d_in, const int* in_sizes, int n_in,
                              void* d_out, int out_size, void* d_ws, size_t ws_size,
                              hipStream_t stream) {
    const float* x  = (const float*)d_in[0];
    const float* W1 = (const float*)d_in[1];
    const float* b1 = (const float*)d_in[2];
    const float* W2 = (const float*)d_in[3];
    const float* b2 = (const float*)d_in[4];
    float* out = (float*)d_out;
    float* wt  = (float*)d_ws;       // 1280 floats: W1T
    int nrows = in_sizes[0] / S_LEN;
    int blocks = (nrows + 3) / 4;    // wave per row
    transpose_w_kernel<<<2, 256, 0, stream>>>(W1, wt);
    fused_stats_mlp_kernel<<<blocks, 256, 0, stream>>>(x, wt, b1, W2, b2, out, nrows);
}